// Round 2
// baseline (836.310 us; speedup 1.0000x reference)
//
#include <hip/hip_runtime.h>

// Problem constants (from reference)
#define NB      128   // batch
#define ND      8     // input dims
#define NK      8     // regimes
#define TLEN    512
#define NSTEPS  496   // T - CAPACITY
#define HCOLS   527   // 15 (left pad) + 512 stream columns
#define QMAX    510   // last stream position = 495 + 15

__device__ __forceinline__ float eluf(float x) {
    return x > 0.f ? x : expm1f(x);   // jax.nn.elu uses expm1
}

// 32-term dot: col is an LDS column (32 floats, 16B-aligned), w is a register array
__device__ __forceinline__ float dot32(const float* col, const float* w) {
    const float4* cp = (const float4*)col;
    float a0 = 0.f, a1 = 0.f, a2 = 0.f, a3 = 0.f;
    #pragma unroll
    for (int i = 0; i < 8; ++i) {
        float4 v = cp[i];
        float t = w[4*i]*v.x + w[4*i+1]*v.y + w[4*i+2]*v.z + w[4*i+3]*v.w;
        if ((i & 3) == 0) a0 += t;
        else if ((i & 3) == 1) a1 += t;
        else if ((i & 3) == 2) a2 += t;
        else a3 += t;
    }
    return (a0 + a1) + (a2 + a3);
}

__global__ __launch_bounds__(64, 1)
void regime_scan_kernel(const float* __restrict__ xg,
                        const float* __restrict__ tempg,
                        const float* __restrict__ ug,
                        const float* __restrict__ w0g,
                        const float* __restrict__ b0g,
                        const float* __restrict__ w1g,
                        const float* __restrict__ b1g,
                        const float* __restrict__ w2g,
                        const float* __restrict__ b2g,
                        const float* __restrict__ w3g,
                        const float* __restrict__ b3g,
                        float* __restrict__ outg)
{
    // Streaming state. hcol = concat(xpad, z) columns over the whole stream.
    __shared__ float hcol[HCOLS][16];        // 33.7 KB
    __shared__ float r0[4][32];              // layer0 ring (need q, q-2)
    __shared__ float r1[8][32];              // layer1 ring (need q, q-4)
    __shared__ float r2[16][32];             // layer2 ring (need q, q-8)
    __shared__ float gls[NSTEPS * NK];       // Gumbel noise, 15.9 KB

    const int lane = threadIdx.x;
    const int b    = blockIdx.x;
    const int c    = lane & 31;    // output channel for layers 0-2
    const int h    = lane >> 5;    // conv tap (0 = old col, 1 = newest col)
    const int c3   = lane & 7;     // output channel for layer 3
    const int j3   = lane >> 3;    // K-slice for layer 3
    const int tap3 = j3 & 1;
    const int i03  = (j3 >> 1) * 8;

    // ---- weights -> registers (per-lane slices) ----
    float w0r[16], w1r[32], w2r[32], w3r[8];
    #pragma unroll
    for (int i = 0; i < 16; ++i) w0r[i] = w0g[c * 32 + i * 2 + h];
    #pragma unroll
    for (int i = 0; i < 32; ++i) w1r[i] = w1g[c * 64 + i * 2 + h];
    #pragma unroll
    for (int i = 0; i < 32; ++i) w2r[i] = w2g[c * 64 + i * 2 + h];
    #pragma unroll
    for (int i = 0; i < 8; ++i)  w3r[i] = w3g[c3 * 64 + (i03 + i) * 2 + tap3];
    const float b0r = b0g[c];
    const float b1r = b1g[c];
    const float b2r = b2g[c];
    const float b3r = b3g[c3];
    const float tinv = 1.0f / tempg[0];

    // ---- stage: zero pads + z channels, load x row, precompute gumbel noise ----
    for (int p = lane; p < HCOLS; p += 64) {
        #pragma unroll
        for (int k = 0; k < 8; ++k) hcol[p][8 + k] = 0.f;
        if (p < 15) {
            #pragma unroll
            for (int d = 0; d < 8; ++d) hcol[p][d] = 0.f;
        }
    }
    const float* xb = xg + b * (ND * TLEN);
    #pragma unroll
    for (int d = 0; d < ND; ++d)
        for (int t = lane; t < TLEN; t += 64)
            hcol[15 + t][d] = xb[d * TLEN + t];

    for (int idx = lane; idx < NSTEPS * NK; idx += 64) {
        int s = idx >> 3, k = idx & 7;
        float uu = ug[s * (NB * NK) + b * NK + k];
        gls[idx] = -logf(-logf(uu + 1e-10f) + 1e-10f);
    }

    // z_all[:, :, 0:16] = 0 (d_out is poisoned before every launch)
    const int zoff = b * (NK * TLEN);
    const int qoff = NB * NK * TLEN + b * (NK * NSTEPS);
    for (int idx = lane; idx < NK * 16; idx += 64) {
        int k = idx >> 4, t = idx & 15;
        outg[zoff + k * TLEN + t] = 0.f;
    }
    __syncthreads();

    // ---- streaming scan over global positions q; output step s = q-15 ----
    for (int q = 1; q <= QMAX; ++q) {
        // Layer 0: 32ch <- 16ch, taps at q-1 and q
        {
            const float4* cp = (const float4*)(&hcol[q - 1 + h][0]);
            float4 v0 = cp[0], v1 = cp[1], v2 = cp[2], v3 = cp[3];
            float aA = w0r[0]*v0.x + w0r[1]*v0.y + w0r[2]*v0.z + w0r[3]*v0.w
                     + w0r[4]*v1.x + w0r[5]*v1.y + w0r[6]*v1.z + w0r[7]*v1.w;
            float aB = w0r[8]*v2.x  + w0r[9]*v2.y  + w0r[10]*v2.z + w0r[11]*v2.w
                     + w0r[12]*v3.x + w0r[13]*v3.y + w0r[14]*v3.z + w0r[15]*v3.w;
            float s = aA + aB;
            s += __shfl_down(s, 32);
            float o = eluf(s + b0r);
            if (lane < 32) r0[q & 3][c] = o;
        }
        __syncthreads();
        // Layer 1: taps at q-2 and q
        if (q >= 3) {
            float s = dot32(&r0[(q - 2 + 2 * h) & 3][0], w1r);
            s += __shfl_down(s, 32);
            float o = eluf(s + b1r);
            if (lane < 32) r1[q & 7][c] = o;
        }
        __syncthreads();
        // Layer 2: taps at q-4 and q
        if (q >= 7) {
            float s = dot32(&r1[(q - 4 + 4 * h) & 7][0], w2r);
            s += __shfl_down(s, 32);
            float o = eluf(s + b2r);
            if (lane < 32) r2[q & 15][c] = o;
        }
        __syncthreads();
        // Layer 3 + softmaxes + feedback, only valid from q = 15
        if (q >= 15) {
            const float4* cp = (const float4*)(&r2[(q - 8 + 8 * tap3) & 15][i03]);
            float4 v0 = cp[0], v1 = cp[1];
            float p = w3r[0]*v0.x + w3r[1]*v0.y + w3r[2]*v0.z + w3r[3]*v0.w
                    + w3r[4]*v1.x + w3r[5]*v1.y + w3r[6]*v1.z + w3r[7]*v1.w;
            p += __shfl_down(p, 32);
            p += __shfl_down(p, 16);
            p += __shfl_down(p, 8);
            float a3 = eluf(p + b3r);        // lanes 0..7 hold a3[c3]

            // log_softmax over 8 regime lanes
            float m = a3;
            m = fmaxf(m, __shfl_xor(m, 1));
            m = fmaxf(m, __shfl_xor(m, 2));
            m = fmaxf(m, __shfl_xor(m, 4));
            float e = expf(a3 - m);
            float se = e;
            se += __shfl_xor(se, 1);
            se += __shfl_xor(se, 2);
            se += __shfl_xor(se, 4);
            float lq = (a3 - m) - logf(se);

            // gumbel-softmax sample
            const int s_idx = q - 15;
            float g  = gls[s_idx * NK + c3];
            float t2 = (lq + g) * tinv;
            float m2 = t2;
            m2 = fmaxf(m2, __shfl_xor(m2, 1));
            m2 = fmaxf(m2, __shfl_xor(m2, 2));
            m2 = fmaxf(m2, __shfl_xor(m2, 4));
            float e2 = expf(t2 - m2);
            float s2 = e2;
            s2 += __shfl_xor(s2, 1);
            s2 += __shfl_xor(s2, 2);
            s2 += __shfl_xor(s2, 4);
            float y = e2 / s2;

            if (lane < 8) {
                hcol[q + 1][8 + c3] = y;                         // feedback z column
                outg[zoff + c3 * TLEN + (q + 1)]   = y;          // z_all[b][c3][16+s]
                outg[qoff + c3 * NSTEPS + s_idx]   = lq;         // logq[b][c3][s][0]
            }
        }
        __syncthreads();
    }
}

extern "C" void kernel_launch(void* const* d_in, const int* in_sizes, int n_in,
                              void* d_out, int out_size, void* d_ws, size_t ws_size,
                              hipStream_t stream) {
    (void)in_sizes; (void)n_in; (void)out_size; (void)d_ws; (void)ws_size;
    regime_scan_kernel<<<dim3(NB), dim3(64), 0, stream>>>(
        (const float*)d_in[0],   // x
        (const float*)d_in[1],   // temp
        (const float*)d_in[2],   // u
        (const float*)d_in[3],   // w0
        (const float*)d_in[4],   // b0
        (const float*)d_in[5],   // w1
        (const float*)d_in[6],   // b1
        (const float*)d_in[7],   // w2
        (const float*)d_in[8],   // b2
        (const float*)d_in[9],   // w3
        (const float*)d_in[10],  // b3
        (float*)d_out);
}